// Round 9
// baseline (343.168 us; speedup 1.0000x reference)
//
#include <hip/hip_runtime.h>
#include <cstdint>

#define BB   128
#define SS   256
#define NDEPTH 655
#define UU   128
#define VV   512   // 4*UU
#define NPB  32

// ---------------- context features + sequence_length scalar ----------------
__global__ void context_kernel(const int* __restrict__ last_rule,
                               const int* __restrict__ move_count,
                               const int* __restrict__ node_count,
                               const int* __restrict__ problem_type,
                               float* __restrict__ out, int write_seq) {
    int i = blockIdx.x * blockDim.x + threadIdx.x;
    if (i < BB * 35) {
        int b = i / 35, c = i % 35;
        float v;
        if (c == 0)      v = (float)last_rule[b];
        else if (c == 1) v = (float)move_count[b];
        else if (c == 2) v = (float)node_count[b];
        else             v = (problem_type[b] == (c - 3)) ? 1.0f : 0.0f;
        out[i] = v;
    }
    if (write_seq && i == 0)
        out[(size_t)BB*35 + (size_t)BB*UU + (size_t)BB*SS*UU] = (float)SS;
}

// ---------------- WdWx = W_dense @ Wx  (2620 x 512), base = b_dense@Wx + b_lstm ----
__global__ void wdwx_kernel(const float* __restrict__ Wd,      // [2620,128]
                            const float* __restrict__ Wx,      // [128,512]
                            const float* __restrict__ b_dense, // [128]
                            const float* __restrict__ b_lstm,  // [512]
                            float* __restrict__ WdWx,          // [2620,512]
                            float* __restrict__ base) {        // [512]
    int v  = threadIdx.x;          // 0..511
    int k0 = blockIdx.x * 4;       // 655 blocks, 4 rows each
    const float* wd0 = Wd + (size_t)k0 * UU;   // block-uniform -> scalar loads
    float a0 = 0.f, a1 = 0.f, a2 = 0.f, a3 = 0.f;
    for (int u = 0; u < UU; ++u) {
        float wx = Wx[u * VV + v];             // coalesced, L2-resident
        a0 = fmaf(wd0[u],        wx, a0);
        a1 = fmaf(wd0[UU + u],   wx, a1);
        a2 = fmaf(wd0[2*UU + u], wx, a2);
        a3 = fmaf(wd0[3*UU + u], wx, a3);
    }
    WdWx[(size_t)(k0+0)*VV + v] = a0;
    WdWx[(size_t)(k0+1)*VV + v] = a1;
    WdWx[(size_t)(k0+2)*VV + v] = a2;
    WdWx[(size_t)(k0+3)*VV + v] = a3;
    if (blockIdx.x == 0) {
        float a = 0.f;
        for (int u = 0; u < UU; ++u) a = fmaf(b_dense[u], Wx[u * VV + v], a);
        base[v] = a + b_lstm[v];
    }
}

// ---------------- persistent per-batch LSTM, 1024 thr, split-K x8 ---------
// lane l of wave w: unit u = w*8 + (l>>3), q = l&3 (gate), e = (l>>2)&1.
// Chunk ch = q+4e: thread reads h floats [16ch..16ch+16) (4 b128; chunk
// stride 20 floats -> 8 chunk bases cover all 32 banks, conflict-free) and
// computes partials for all 4 gates of unit u over its 16 floats (64 FMA,
// wh[64] fully static). Gathers for gate q, panels {2e,2e+1} fold into
// pp[q]. Quad butterfly (R8-validated) + shfl_xor(.,4) -> full z per gate.
// Gate exchange + cell update replicated x8. One barrier per step.
// 16 waves = 4/SIMD: latency chains overlap across waves (R8: 2/SIMD left
// ~1280 idle cyc/step).
__global__ __launch_bounds__(1024, 4)
void lstm_kernel(const int* __restrict__ bwd,  const int* __restrict__ fwd,
                 const int* __restrict__ lbwd, const int* __restrict__ lfwd,
                 const float* __restrict__ WdWx,   // [2620,512]
                 const float* __restrict__ base,   // [512]
                 const float* __restrict__ Wh,     // [128,512]
                 float* __restrict__ hidden_states, // [B,S,U]
                 float* __restrict__ lstm_vectors) {// [B,U]
    const int b    = blockIdx.x;
    const int t    = threadIdx.x;     // 0..1023
    const int lane = t & 63;
    const int w    = t >> 6;          // wave 0..15
    const int q    = lane & 3;        // gate (keras i,f,g,o)
    const int e    = (lane >> 2) & 1; // K-half
    const int u    = w * 8 + (lane >> 3);    // unit 0..127
    const int col  = q * UU + u;             // this thread's gate column
    const int ch   = q + 4 * e;              // h-chunk 0..7

    // h chunks: chunk j at float offset 20*j (bank bases 20j%32 all distinct)
    __shared__ __align__(16) float h_buf[2][160];
    __shared__ int idx_lds[SS][4];

    // wh[kk*4+g] = Wh[16ch+kk][g*128+u] — FULL static unroll (rule #20:
    // any runtime index -> scratch; R5: 8x slowdown)
    float wh[64];
    #pragma unroll
    for (int kk = 0; kk < 16; ++kk) {
        #pragma unroll
        for (int g = 0; g < 4; ++g)
            wh[kk*4+g] = Wh[(size_t)(16*ch + kk) * VV + g*UU + u];
    }

    for (int s = t; s < SS; s += 1024) {
        idx_lds[s][0] =            bwd [b*SS + s];
        idx_lds[s][1] =   NDEPTH + fwd [b*SS + s];
        idx_lds[s][2] = 2*NDEPTH + lbwd[b*SS + s];
        idx_lds[s][3] = 3*NDEPTH + lfwd[b*SS + s];
    }
    if (t < UU) h_buf[0][20*(t>>4) + (t&15)] = 0.0f;
    float c    = 0.0f;                 // cell state, replicated x8
    float bias = base[col];
    __syncthreads();

    // prefetch step-0 gather: panels 2e, 2e+1 of this thread's column
    float g0 = WdWx[(size_t)idx_lds[0][2*e    ] * VV + col];
    float g1 = WdWx[(size_t)idx_lds[0][2*e + 1] * VV + col];

    const bool b0 = (q & 1) != 0;
    const bool b1 = (q & 2) != 0;

    int p = 0;
    for (int s = 0; s < SS; ++s) {
        float gsum = g0 + g1;
        if (s + 1 < SS) {              // prefetch next step under the dot
            g0 = WdWx[(size_t)idx_lds[s+1][2*e    ] * VV + col];
            g1 = WdWx[(size_t)idx_lds[s+1][2*e + 1] * VV + col];
        }

        // partial dots over my 16-float chunk for all 4 gates of unit u;
        // my gathers (gate q) seed pp[q]
        float pp0 = (q == 0) ? gsum : 0.f;
        float pp1 = (q == 1) ? gsum : 0.f;
        float pp2 = (q == 2) ? gsum : 0.f;
        float pp3 = (q == 3) ? gsum : 0.f;
        const float* hb = h_buf[p] + 20 * ch;
        #pragma unroll
        for (int kk = 0; kk < 16; kk += 4) {
            float4 hv = *(const float4*)(hb + kk);
            pp0 = fmaf(hv.x, wh[(kk+0)*4+0], pp0);
            pp1 = fmaf(hv.x, wh[(kk+0)*4+1], pp1);
            pp2 = fmaf(hv.x, wh[(kk+0)*4+2], pp2);
            pp3 = fmaf(hv.x, wh[(kk+0)*4+3], pp3);
            pp0 = fmaf(hv.y, wh[(kk+1)*4+0], pp0);
            pp1 = fmaf(hv.y, wh[(kk+1)*4+1], pp1);
            pp2 = fmaf(hv.y, wh[(kk+1)*4+2], pp2);
            pp3 = fmaf(hv.y, wh[(kk+1)*4+3], pp3);
            pp0 = fmaf(hv.z, wh[(kk+2)*4+0], pp0);
            pp1 = fmaf(hv.z, wh[(kk+2)*4+1], pp1);
            pp2 = fmaf(hv.z, wh[(kk+2)*4+2], pp2);
            pp3 = fmaf(hv.z, wh[(kk+2)*4+3], pp3);
            pp0 = fmaf(hv.w, wh[(kk+3)*4+0], pp0);
            pp1 = fmaf(hv.w, wh[(kk+3)*4+1], pp1);
            pp2 = fmaf(hv.w, wh[(kk+3)*4+2], pp2);
            pp3 = fmaf(hv.w, wh[(kk+3)*4+3], pp3);
        }

        // quad transpose-reduce (R8-validated): thread q <- sum_q' pp_q'[q]
        float keepA = b0 ? pp1 : pp0;
        float keepB = b0 ? pp3 : pp2;
        float sendA = b0 ? pp0 : pp1;
        float sendB = b0 ? pp2 : pp3;
        float sA = keepA + __shfl_xor(sendA, 1);
        float sB = keepB + __shfl_xor(sendB, 1);
        float send2 = b1 ? sA : sB;
        float zh = (b1 ? sB : sA) + __shfl_xor(send2, 2);
        // combine K-halves (and the other 2 gather panels)
        float z = bias + zh + __shfl_xor(zh, 4);

        // activation: sigmoid; gate 2 (g) = tanh via 2*sigm(2z)-1
        float xs = (q == 2) ? 2.0f * z : z;
        float sg = __fdividef(1.0f, 1.0f + __expf(-xs));
        float a  = (q == 2) ? 2.0f * sg - 1.0f : sg;

        // quad exchange: v1 = act(q^1), v2 = act(q^2), v3 = act(q^3)
        float v1 = __shfl_xor(a, 1);
        float v2 = __shfl_xor(a, 2);
        float v3 = __shfl_xor(v1, 2);
        float ig = (q & 1) ? v1 * v3 : a * v2;                    // i*g
        float gf = (q & 1) ? ((q & 2) ? v2 : a)
                           : ((q & 2) ? v3 : v1);                 // f
        float go = (q & 1) ? ((q & 2) ? a  : v2)
                           : ((q & 2) ? v1 : v3);                 // o
        c = fmaf(gf, c, ig);
        float ex = __expf(2.0f * c);
        float tc = 1.0f - __fdividef(2.0f, ex + 1.0f);            // tanh(c)
        float h  = go * tc;

        if ((lane & 7) == 0) {         // one writer per unit
            h_buf[p ^ 1][20*(u>>4) + (u&15)] = h;
            hidden_states[((size_t)b * SS + s) * UU + u] = h;
        }
        __syncthreads();               // single barrier: h ready, WAR safe
        p ^= 1;
    }
    if (t < UU) lstm_vectors[(size_t)b * UU + t] = h_buf[p][20*(t>>4) + (t&15)];
}

// ---------------------------------------------------------------------------
extern "C" void kernel_launch(void* const* d_in, const int* in_sizes, int n_in,
                              void* d_out, int out_size, void* d_ws, size_t ws_size,
                              hipStream_t stream) {
    const int* move_count   = (const int*)d_in[0];
    // d_in[1] moves_remaining: unused by the reference
    const int* last_rule    = (const int*)d_in[2];
    const int* node_count   = (const int*)d_in[3];
    const int* problem_type = (const int*)d_in[4];
    const int* bwd          = (const int*)d_in[5];
    const int* fwd          = (const int*)d_in[6];
    const int* lbwd         = (const int*)d_in[7];
    const int* lfwd         = (const int*)d_in[8];
    const float* Wd         = (const float*)d_in[9];
    const float* b_dense    = (const float*)d_in[10];
    const float* Wx         = (const float*)d_in[11];
    const float* Wh         = (const float*)d_in[12];
    const float* b_lstm     = (const float*)d_in[13];

    float* out  = (float*)d_out;
    float* WdWx = (float*)d_ws;                        // 2620*512*4 = 5.37 MB
    float* base = WdWx + (size_t)(4 * NDEPTH) * VV;    // +512 floats

    float* lstm_out = out + BB * 35;
    float* hs_out   = lstm_out + BB * UU;
    int write_seq = (out_size > BB*35 + BB*UU + BB*SS*UU) ? 1 : 0;

    context_kernel<<<(BB*35 + 255)/256, 256, 0, stream>>>(
        last_rule, move_count, node_count, problem_type, out, write_seq);
    wdwx_kernel<<<NDEPTH, VV, 0, stream>>>(Wd, Wx, b_dense, b_lstm, WdWx, base);
    lstm_kernel<<<BB, 1024, 0, stream>>>(bwd, fwd, lbwd, lfwd, WdWx, base, Wh,
                                         hs_out, lstm_out);
}

// Round 10
// 316.935 us; speedup vs baseline: 1.0828x; 1.0828x over previous
//
#include <hip/hip_runtime.h>
#include <cstdint>

#define BB   128
#define SS   256
#define NDEPTH 655
#define UU   128
#define VV   512   // 4*UU
#define NPB  32

// Raw barrier (HK pattern): LDS-ordering only — does NOT drain vmcnt, so the
// per-step hidden_states global store and gather prefetches stay in flight
// across the barrier. __syncthreads() would emit s_waitcnt vmcnt(0) and
// serialize a ~200-400cyc store-retire tail into EVERY step (m97 finding).
#define STEP_BARRIER()                                          \
    do {                                                        \
        asm volatile("s_waitcnt lgkmcnt(0)" ::: "memory");      \
        __builtin_amdgcn_s_barrier();                           \
        __builtin_amdgcn_sched_barrier(0);                      \
    } while (0)

// ---------------- context features + sequence_length scalar ----------------
__global__ void context_kernel(const int* __restrict__ last_rule,
                               const int* __restrict__ move_count,
                               const int* __restrict__ node_count,
                               const int* __restrict__ problem_type,
                               float* __restrict__ out, int write_seq) {
    int i = blockIdx.x * blockDim.x + threadIdx.x;
    if (i < BB * 35) {
        int b = i / 35, c = i % 35;
        float v;
        if (c == 0)      v = (float)last_rule[b];
        else if (c == 1) v = (float)move_count[b];
        else if (c == 2) v = (float)node_count[b];
        else             v = (problem_type[b] == (c - 3)) ? 1.0f : 0.0f;
        out[i] = v;
    }
    if (write_seq && i == 0)
        out[(size_t)BB*35 + (size_t)BB*UU + (size_t)BB*SS*UU] = (float)SS;
}

// ---------------- WdWx = W_dense @ Wx  (2620 x 512), base = b_dense@Wx + b_lstm ----
__global__ void wdwx_kernel(const float* __restrict__ Wd,      // [2620,128]
                            const float* __restrict__ Wx,      // [128,512]
                            const float* __restrict__ b_dense, // [128]
                            const float* __restrict__ b_lstm,  // [512]
                            float* __restrict__ WdWx,          // [2620,512]
                            float* __restrict__ base) {        // [512]
    int v  = threadIdx.x;          // 0..511
    int k0 = blockIdx.x * 4;       // 655 blocks, 4 rows each
    const float* wd0 = Wd + (size_t)k0 * UU;   // block-uniform -> scalar loads
    float a0 = 0.f, a1 = 0.f, a2 = 0.f, a3 = 0.f;
    for (int u = 0; u < UU; ++u) {
        float wx = Wx[u * VV + v];             // coalesced, L2-resident
        a0 = fmaf(wd0[u],        wx, a0);
        a1 = fmaf(wd0[UU + u],   wx, a1);
        a2 = fmaf(wd0[2*UU + u], wx, a2);
        a3 = fmaf(wd0[3*UU + u], wx, a3);
    }
    WdWx[(size_t)(k0+0)*VV + v] = a0;
    WdWx[(size_t)(k0+1)*VV + v] = a1;
    WdWx[(size_t)(k0+2)*VV + v] = a2;
    WdWx[(size_t)(k0+3)*VV + v] = a3;
    if (blockIdx.x == 0) {
        float a = 0.f;
        for (int u = 0; u < UU; ++u) a = fmaf(b_dense[u], Wx[u * VV + v], a);
        base[v] = a + b_lstm[v];
    }
}

// ---------------- persistent per-batch LSTM, quad-gate + quad-split-K -----
// R8 structure (best measured: 228 us): 512 thr, unit u = w*16+(l>>2),
// q = l&3. Thread q reads h-chunk [32q..32q+32) (8 b128, stride-36 bank
// stagger), partials for all 4 gates (wh[128] fully static), quad butterfly
// (shfl_xor 1,2) -> full dot for gate q. One RAW barrier per step.
__global__ __launch_bounds__(512, 2)
void lstm_kernel(const int* __restrict__ bwd,  const int* __restrict__ fwd,
                 const int* __restrict__ lbwd, const int* __restrict__ lfwd,
                 const float* __restrict__ WdWx,   // [2620,512]
                 const float* __restrict__ base,   // [512]
                 const float* __restrict__ Wh,     // [128,512]
                 float* __restrict__ hidden_states, // [B,S,U]
                 float* __restrict__ lstm_vectors) {// [B,U]
    const int b    = blockIdx.x;
    const int t    = threadIdx.x;     // 0..511
    const int lane = t & 63;
    const int w    = t >> 6;          // wave 0..7
    const int q    = lane & 3;        // gate lane (keras i,f,g,o)
    const int u    = w * 16 + (lane >> 2);   // unit 0..127
    const int col  = q * UU + u;             // this thread's gate column

    // h chunks: chunk j at float offset 36*j (banks 4j..4j+3 for b128 reads)
    __shared__ __align__(16) float h_buf[2][144];
    __shared__ int idx_lds[SS][4];

    // wh[kk*4+g] = Wh[32q+kk][g*128+u] — FULL static unroll (rule #20:
    // any runtime index -> scratch, R5: 8x slowdown)
    float wh[128];
    #pragma unroll
    for (int kk = 0; kk < 32; ++kk) {
        #pragma unroll
        for (int g = 0; g < 4; ++g)
            wh[kk*4+g] = Wh[(size_t)(32*q + kk) * VV + g*UU + u];
    }

    for (int s = t; s < SS; s += 512) {
        idx_lds[s][0] =            bwd [b*SS + s];
        idx_lds[s][1] =   NDEPTH + fwd [b*SS + s];
        idx_lds[s][2] = 2*NDEPTH + lbwd[b*SS + s];
        idx_lds[s][3] = 3*NDEPTH + lfwd[b*SS + s];
    }
    if (t < UU) h_buf[0][36*(t>>5) + (t&31)] = 0.0f;
    float c    = 0.0f;                 // cell state, replicated per quad
    float bias = base[col];
    __syncthreads();                   // one full barrier at init is fine

    // prefetch step-0 gather
    float g0 = WdWx[(size_t)idx_lds[0][0] * VV + col];
    float g1 = WdWx[(size_t)idx_lds[0][1] * VV + col];
    float g2 = WdWx[(size_t)idx_lds[0][2] * VV + col];
    float g3 = WdWx[(size_t)idx_lds[0][3] * VV + col];

    const bool b0 = (q & 1) != 0;
    const bool b1 = (q & 2) != 0;

    int p = 0;
    for (int s = 0; s < SS; ++s) {
        float z = bias + (g0 + g1) + (g2 + g3);
        if (s + 1 < SS) {              // prefetch next step under the dot
            g0 = WdWx[(size_t)idx_lds[s+1][0] * VV + col];
            g1 = WdWx[(size_t)idx_lds[s+1][1] * VV + col];
            g2 = WdWx[(size_t)idx_lds[s+1][2] * VV + col];
            g3 = WdWx[(size_t)idx_lds[s+1][3] * VV + col];
        }

        // partial dots over my 32-chunk for all 4 gates of unit u
        const float* hb = h_buf[p] + 36 * q;
        float pp0 = 0.f, pp1 = 0.f, pp2 = 0.f, pp3 = 0.f;
        #pragma unroll
        for (int kk = 0; kk < 32; kk += 4) {
            float4 hv = *(const float4*)(hb + kk);
            pp0 = fmaf(hv.x, wh[(kk+0)*4+0], pp0);
            pp1 = fmaf(hv.x, wh[(kk+0)*4+1], pp1);
            pp2 = fmaf(hv.x, wh[(kk+0)*4+2], pp2);
            pp3 = fmaf(hv.x, wh[(kk+0)*4+3], pp3);
            pp0 = fmaf(hv.y, wh[(kk+1)*4+0], pp0);
            pp1 = fmaf(hv.y, wh[(kk+1)*4+1], pp1);
            pp2 = fmaf(hv.y, wh[(kk+1)*4+2], pp2);
            pp3 = fmaf(hv.y, wh[(kk+1)*4+3], pp3);
            pp0 = fmaf(hv.z, wh[(kk+2)*4+0], pp0);
            pp1 = fmaf(hv.z, wh[(kk+2)*4+1], pp1);
            pp2 = fmaf(hv.z, wh[(kk+2)*4+2], pp2);
            pp3 = fmaf(hv.z, wh[(kk+2)*4+3], pp3);
            pp0 = fmaf(hv.w, wh[(kk+3)*4+0], pp0);
            pp1 = fmaf(hv.w, wh[(kk+3)*4+1], pp1);
            pp2 = fmaf(hv.w, wh[(kk+3)*4+2], pp2);
            pp3 = fmaf(hv.w, wh[(kk+3)*4+3], pp3);
        }

        // quad transpose-reduce: thread q <- sum_q' partial[gate q]
        float keepA = b0 ? pp1 : pp0;          // gate b0
        float keepB = b0 ? pp3 : pp2;          // gate b0+2
        float sendA = b0 ? pp0 : pp1;
        float sendB = b0 ? pp2 : pp3;
        float sA = keepA + __shfl_xor(sendA, 1);
        float sB = keepB + __shfl_xor(sendB, 1);
        float send2 = b1 ? sA : sB;
        z += (b1 ? sB : sA) + __shfl_xor(send2, 2);

        // activation: sigmoid; gate 2 (g) = tanh via 2*sigm(2z)-1
        float xs = (q == 2) ? 2.0f * z : z;
        float sg = __fdividef(1.0f, 1.0f + __expf(-xs));
        float a  = (q == 2) ? 2.0f * sg - 1.0f : sg;

        // quad exchange: v1 = act(q^1), v2 = act(q^2), v3 = act(q^3)
        float v1 = __shfl_xor(a, 1);
        float v2 = __shfl_xor(a, 2);
        float v3 = __shfl_xor(v1, 2);
        float ig = (q & 1) ? v1 * v3 : a * v2;                    // i*g
        float gf = (q & 1) ? ((q & 2) ? v2 : a)
                           : ((q & 2) ? v3 : v1);                 // f
        float go = (q & 1) ? ((q & 2) ? a  : v2)
                           : ((q & 2) ? v1 : v3);                 // o
        c = fmaf(gf, c, ig);
        float e  = __expf(2.0f * c);
        float tc = 1.0f - __fdividef(2.0f, e + 1.0f);             // tanh(c)
        float h  = go * tc;

        if (q == 0) {
            h_buf[p ^ 1][36*(u>>5) + (u&31)] = h;
            hidden_states[((size_t)b * SS + s) * UU + u] = h;   // fire & forget
        }
        STEP_BARRIER();                // lgkmcnt-only: store stays in flight
        p ^= 1;
    }
    if (t < UU) lstm_vectors[(size_t)b * UU + t] = h_buf[p][36*(t>>5) + (t&31)];
}

// ---------------------------------------------------------------------------
extern "C" void kernel_launch(void* const* d_in, const int* in_sizes, int n_in,
                              void* d_out, int out_size, void* d_ws, size_t ws_size,
                              hipStream_t stream) {
    const int* move_count   = (const int*)d_in[0];
    // d_in[1] moves_remaining: unused by the reference
    const int* last_rule    = (const int*)d_in[2];
    const int* node_count   = (const int*)d_in[3];
    const int* problem_type = (const int*)d_in[4];
    const int* bwd          = (const int*)d_in[5];
    const int* fwd          = (const int*)d_in[6];
    const int* lbwd         = (const int*)d_in[7];
    const int* lfwd         = (const int*)d_in[8];
    const float* Wd         = (const float*)d_in[9];
    const float* b_dense    = (const float*)d_in[10];
    const float* Wx         = (const float*)d_in[11];
    const float* Wh         = (const float*)d_in[12];
    const float* b_lstm     = (const float*)d_in[13];

    float* out  = (float*)d_out;
    float* WdWx = (float*)d_ws;                        // 2620*512*4 = 5.37 MB
    float* base = WdWx + (size_t)(4 * NDEPTH) * VV;    // +512 floats

    float* lstm_out = out + BB * 35;
    float* hs_out   = lstm_out + BB * UU;
    int write_seq = (out_size > BB*35 + BB*UU + BB*SS*UU) ? 1 : 0;

    context_kernel<<<(BB*35 + 255)/256, 256, 0, stream>>>(
        last_rule, move_count, node_count, problem_type, out, write_seq);
    wdwx_kernel<<<NDEPTH, VV, 0, stream>>>(Wd, Wx, b_dense, b_lstm, WdWx, base);
    lstm_kernel<<<BB, 512, 0, stream>>>(bwd, fwd, lbwd, lfwd, WdWx, base, Wh,
                                        hs_out, lstm_out);
}

// Round 11
// 308.997 us; speedup vs baseline: 1.1106x; 1.0257x over previous
//
#include <hip/hip_runtime.h>
#include <cstdint>

#define BB   128
#define SS   256
#define NDEPTH 655
#define UU   128
#define VV   512   // 4*UU
#define NPB  32
#define ROWS_PER_BLK 20   // 131 blocks x 20 = 2620 rows of WdWx

typedef _Float16 f16;
typedef _Float16 f16x2 __attribute__((ext_vector_type(2)));

#if __has_builtin(__builtin_amdgcn_fdot2)
#define FDOT2(a, b, c) __builtin_amdgcn_fdot2((a), (b), (c), false)
#else
static __device__ __forceinline__ float FDOT2(f16x2 a, f16x2 b, float c) {
    return c + (float)a.x * (float)b.x + (float)a.y * (float)b.y;
}
#endif

// Raw barrier: LDS-ordering only (R10: neutral vs __syncthreads, kept since
// it is proven-correct and strictly weaker).
#define STEP_BARRIER()                                          \
    do {                                                        \
        asm volatile("s_waitcnt lgkmcnt(0)" ::: "memory");      \
        __builtin_amdgcn_s_barrier();                           \
        __builtin_amdgcn_sched_barrier(0);                      \
    } while (0)

// ------ fused: context features + WdWx = W_dense@Wx + base (+seq scalar) ---
__global__ void wdwx_kernel(const float* __restrict__ Wd,      // [2620,128]
                            const float* __restrict__ Wx,      // [128,512]
                            const float* __restrict__ b_dense, // [128]
                            const float* __restrict__ b_lstm,  // [512]
                            const int* __restrict__ last_rule,
                            const int* __restrict__ move_count,
                            const int* __restrict__ node_count,
                            const int* __restrict__ problem_type,
                            float* __restrict__ WdWx,          // [2620,512]
                            float* __restrict__ base,          // [512]
                            float* __restrict__ out, int write_seq) {
    const int v  = threadIdx.x;          // 0..511
    const int k0 = blockIdx.x * ROWS_PER_BLK;

    // context features (first 9 blocks cover BB*35 = 4480 elements)
    int gid = blockIdx.x * 512 + v;
    if (gid < BB * 35) {
        int b = gid / 35, cc = gid % 35;
        float val;
        if (cc == 0)      val = (float)last_rule[b];
        else if (cc == 1) val = (float)move_count[b];
        else if (cc == 2) val = (float)node_count[b];
        else              val = (problem_type[b] == (cc - 3)) ? 1.0f : 0.0f;
        out[gid] = val;
    }
    if (write_seq && gid == 0)
        out[(size_t)BB*35 + (size_t)BB*UU + (size_t)BB*SS*UU] = (float)SS;

    float acc[ROWS_PER_BLK] = {};        // static-indexed (rule #20)
    for (int uu = 0; uu < UU; ++uu) {
        float wx = Wx[uu * VV + v];      // coalesced; Wx reread 131x (was 655x)
        #pragma unroll
        for (int r = 0; r < ROWS_PER_BLK; ++r)
            acc[r] = fmaf(Wd[(size_t)(k0 + r) * UU + uu], wx, acc[r]);
    }
    #pragma unroll
    for (int r = 0; r < ROWS_PER_BLK; ++r)
        WdWx[(size_t)(k0 + r) * VV + v] = acc[r];

    if (blockIdx.x == 0) {
        float a = 0.f;
        for (int uu = 0; uu < UU; ++uu) a = fmaf(b_dense[uu], Wx[uu * VV + v], a);
        base[v] = a + b_lstm[v];
    }
}

// ---------------- persistent per-batch LSTM, quad split-K, f16 dot --------
// R8 structure (best: 228us) with the recurrent dot in packed f16:
// h mirrored to LDS as f16 (outputs/state stay f32); wh as 64 f16x2 regs;
// 64 v_dot2_f32_f16 + 4 ds_read_b128 per thread per step (was 128 fma + 8).
// Chunk q at byte 80q: bank bases 20q%32 = {0,20,8,28} distinct.
__global__ __launch_bounds__(512, 2)
void lstm_kernel(const int* __restrict__ bwd,  const int* __restrict__ fwd,
                 const int* __restrict__ lbwd, const int* __restrict__ lfwd,
                 const float* __restrict__ WdWx,   // [2620,512]
                 const float* __restrict__ base,   // [512]
                 const float* __restrict__ Wh,     // [128,512]
                 float* __restrict__ hidden_states, // [B,S,U]
                 float* __restrict__ lstm_vectors) {// [B,U]
    const int b    = blockIdx.x;
    const int t    = threadIdx.x;     // 0..511
    const int lane = t & 63;
    const int w    = t >> 6;          // wave 0..7
    const int q    = lane & 3;        // gate lane (keras i,f,g,o)
    const int u    = w * 16 + (lane >> 2);   // unit 0..127
    const int col  = q * UU + u;             // this thread's gate column

    __shared__ __align__(16) unsigned char h2buf[2][320]; // 4 chunks x 80B
    __shared__ int idx_lds[SS][4];

    // wh2[j*4+g] = (Wh[32q+2j][g*128+u], Wh[32q+2j+1][g*128+u]) — FULL static
    // unroll (rule #20: runtime index -> scratch, R5: 8x slowdown)
    f16x2 wh2[64];
    #pragma unroll
    for (int j = 0; j < 16; ++j) {
        #pragma unroll
        for (int g = 0; g < 4; ++g) {
            float w0 = Wh[(size_t)(32*q + 2*j    ) * VV + g*UU + u];
            float w1 = Wh[(size_t)(32*q + 2*j + 1) * VV + g*UU + u];
            f16x2 pk; pk.x = (f16)w0; pk.y = (f16)w1;
            wh2[j*4 + g] = pk;
        }
    }

    for (int s = t; s < SS; s += 512) {
        idx_lds[s][0] =            bwd [b*SS + s];
        idx_lds[s][1] =   NDEPTH + fwd [b*SS + s];
        idx_lds[s][2] = 2*NDEPTH + lbwd[b*SS + s];
        idx_lds[s][3] = 3*NDEPTH + lfwd[b*SS + s];
    }
    if (t < UU)
        ((f16*)(h2buf[0] + 80*(t >> 5)))[t & 31] = (f16)0.0f;
    float c      = 0.0f;               // cell state, replicated per quad (f32)
    float bias   = base[col];
    float h_last = 0.0f;
    __syncthreads();

    // prefetch step-0 gather (f32 rows of WdWx)
    float g0 = WdWx[(size_t)idx_lds[0][0] * VV + col];
    float g1 = WdWx[(size_t)idx_lds[0][1] * VV + col];
    float g2 = WdWx[(size_t)idx_lds[0][2] * VV + col];
    float g3 = WdWx[(size_t)idx_lds[0][3] * VV + col];

    const bool b0 = (q & 1) != 0;
    const bool b1 = (q & 2) != 0;

    int p = 0;
    for (int s = 0; s < SS; ++s) {
        float z = bias + (g0 + g1) + (g2 + g3);
        if (s + 1 < SS) {              // prefetch next step under the dot
            g0 = WdWx[(size_t)idx_lds[s+1][0] * VV + col];
            g1 = WdWx[(size_t)idx_lds[s+1][1] * VV + col];
            g2 = WdWx[(size_t)idx_lds[s+1][2] * VV + col];
            g3 = WdWx[(size_t)idx_lds[s+1][3] * VV + col];
        }

        // partial dots over my 32-h chunk (f16) for all 4 gates of unit u
        const uint4* hb = (const uint4*)(h2buf[p] + 80 * q);
        uint4 A = hb[0], Bv = hb[1], Cv = hb[2], Dv = hb[3];
        float pp0 = 0.f, pp1 = 0.f, pp2 = 0.f, pp3 = 0.f;
        #define DOTW(word, j)                                            \
            do {                                                         \
                f16x2 hv = __builtin_bit_cast(f16x2, (word));            \
                pp0 = FDOT2(hv, wh2[(j)*4+0], pp0);                      \
                pp1 = FDOT2(hv, wh2[(j)*4+1], pp1);                      \
                pp2 = FDOT2(hv, wh2[(j)*4+2], pp2);                      \
                pp3 = FDOT2(hv, wh2[(j)*4+3], pp3);                      \
            } while (0)
        DOTW(A.x,  0); DOTW(A.y,  1); DOTW(A.z,  2); DOTW(A.w,  3);
        DOTW(Bv.x, 4); DOTW(Bv.y, 5); DOTW(Bv.z, 6); DOTW(Bv.w, 7);
        DOTW(Cv.x, 8); DOTW(Cv.y, 9); DOTW(Cv.z,10); DOTW(Cv.w,11);
        DOTW(Dv.x,12); DOTW(Dv.y,13); DOTW(Dv.z,14); DOTW(Dv.w,15);
        #undef DOTW

        // quad transpose-reduce (R8-validated): thread q <- sum_q' pp_q'[q]
        float keepA = b0 ? pp1 : pp0;
        float keepB = b0 ? pp3 : pp2;
        float sendA = b0 ? pp0 : pp1;
        float sendB = b0 ? pp2 : pp3;
        float sA = keepA + __shfl_xor(sendA, 1);
        float sB = keepB + __shfl_xor(sendB, 1);
        float send2 = b1 ? sA : sB;
        z += (b1 ? sB : sA) + __shfl_xor(send2, 2);

        // activation: sigmoid; gate 2 (g) = tanh via 2*sigm(2z)-1
        float xs = (q == 2) ? 2.0f * z : z;
        float sg = __fdividef(1.0f, 1.0f + __expf(-xs));
        float a  = (q == 2) ? 2.0f * sg - 1.0f : sg;

        // quad exchange (R5/R6-validated gate algebra)
        float v1 = __shfl_xor(a, 1);
        float v2 = __shfl_xor(a, 2);
        float v3 = __shfl_xor(v1, 2);
        float ig = (q & 1) ? v1 * v3 : a * v2;                    // i*g
        float gf = (q & 1) ? ((q & 2) ? v2 : a)
                           : ((q & 2) ? v3 : v1);                 // f
        float go = (q & 1) ? ((q & 2) ? a  : v2)
                           : ((q & 2) ? v1 : v3);                 // o
        c = fmaf(gf, c, ig);
        float e  = __expf(2.0f * c);
        float tc = 1.0f - __fdividef(2.0f, e + 1.0f);             // tanh(c)
        float h  = go * tc;

        if (q == 0) {
            ((f16*)(h2buf[p ^ 1] + 80*(u >> 5)))[u & 31] = (f16)h; // dot copy
            hidden_states[((size_t)b * SS + s) * UU + u] = h;      // exact f32
            h_last = h;
        }
        STEP_BARRIER();
        p ^= 1;
    }
    if (q == 0) lstm_vectors[(size_t)b * UU + u] = h_last;
}

// ---------------------------------------------------------------------------
extern "C" void kernel_launch(void* const* d_in, const int* in_sizes, int n_in,
                              void* d_out, int out_size, void* d_ws, size_t ws_size,
                              hipStream_t stream) {
    const int* move_count   = (const int*)d_in[0];
    // d_in[1] moves_remaining: unused by the reference
    const int* last_rule    = (const int*)d_in[2];
    const int* node_count   = (const int*)d_in[3];
    const int* problem_type = (const int*)d_in[4];
    const int* bwd          = (const int*)d_in[5];
    const int* fwd          = (const int*)d_in[6];
    const int* lbwd         = (const int*)d_in[7];
    const int* lfwd         = (const int*)d_in[8];
    const float* Wd         = (const float*)d_in[9];
    const float* b_dense    = (const float*)d_in[10];
    const float* Wx         = (const float*)d_in[11];
    const float* Wh         = (const float*)d_in[12];
    const float* b_lstm     = (const float*)d_in[13];

    float* out  = (float*)d_out;
    float* WdWx = (float*)d_ws;                        // 2620*512*4 = 5.37 MB
    float* base = WdWx + (size_t)(4 * NDEPTH) * VV;    // +512 floats

    float* lstm_out = out + BB * 35;
    float* hs_out   = lstm_out + BB * UU;
    int write_seq = (out_size > BB*35 + BB*UU + BB*SS*UU) ? 1 : 0;

    wdwx_kernel<<<131, VV, 0, stream>>>(Wd, Wx, b_dense, b_lstm,
                                        last_rule, move_count, node_count,
                                        problem_type, WdWx, base, out, write_seq);
    lstm_kernel<<<BB, 512, 0, stream>>>(bwd, fwd, lbwd, lfwd, WdWx, base, Wh,
                                        hs_out, lstm_out);
}